// Round 14
// baseline (1018.944 us; speedup 1.0000x reference)
//
#include <hip/hip_runtime.h>
#include <hip/hip_bf16.h>

#define S_LEN 256
#define NB 32
#define UDIM 512
#define WGS 32    // workgroups per chain

typedef __attribute__((ext_vector_type(8))) short bf16x8;
typedef __attribute__((ext_vector_type(4))) float f32x4;
typedef __attribute__((ext_vector_type(4))) unsigned u32x4;

struct WPtrs { const float* p[8]; };
struct BPtrs { const float* p[4]; };

// hist layout: [c][slot][unit][b][j]  -- each unit owns a CONTIGUOUS 1KB slab
#define SLAB(c, slot) ((((size_t)(c) * 257 + (slot)) * 32) << 10)

__device__ __forceinline__ unsigned short f2bf(float f) {
  union { float f; unsigned u; } v; v.f = f;
  unsigned r = v.u + 0x7fffu + ((v.u >> 16) & 1u);
  return (unsigned short)(r >> 16);
}

// ---- coherent (cross-XCD) memory ops ----
__device__ __forceinline__ unsigned ld_word_coh(const char* p) {
  unsigned v;
  asm volatile("global_load_dword %0, %1, off sc0 sc1\n\ts_waitcnt vmcnt(0)"
               : "=&v"(v) : "v"(p) : "memory");
  return v;
}
__device__ __forceinline__ void st_u32c(void* p, unsigned v) {
  asm volatile("global_store_dword %0, %1, off sc0 sc1" :: "v"(p), "v"(v) : "memory");
}

// Coherent 16-load batch over the unit-slab layout. vmcnt(0) INSIDE the asm;
// returns per-lane "no 0xFFFFFFFF sentinel word" (commit validation).
__device__ __forceinline__ bool ld_slab16(const char* b0, const char* b1,
                                          const char* b2, const char* b3,
                                          bf16x8* afr0, bf16x8* afr1) {
  u32x4 q0,q1,q2,q3,q4,q5,q6,q7,q8,q9,q10,q11,q12,q13,q14,q15;
  asm volatile(
    "global_load_dwordx4 %0, %16, off sc0 sc1\n\t"
    "global_load_dwordx4 %1, %16, off offset:512 sc0 sc1\n\t"
    "global_load_dwordx4 %2, %16, off offset:2048 sc0 sc1\n\t"
    "global_load_dwordx4 %3, %16, off offset:2560 sc0 sc1\n\t"
    "global_load_dwordx4 %4, %17, off sc0 sc1\n\t"
    "global_load_dwordx4 %5, %17, off offset:512 sc0 sc1\n\t"
    "global_load_dwordx4 %6, %17, off offset:2048 sc0 sc1\n\t"
    "global_load_dwordx4 %7, %17, off offset:2560 sc0 sc1\n\t"
    "global_load_dwordx4 %8, %18, off sc0 sc1\n\t"
    "global_load_dwordx4 %9, %18, off offset:512 sc0 sc1\n\t"
    "global_load_dwordx4 %10, %18, off offset:2048 sc0 sc1\n\t"
    "global_load_dwordx4 %11, %18, off offset:2560 sc0 sc1\n\t"
    "global_load_dwordx4 %12, %19, off sc0 sc1\n\t"
    "global_load_dwordx4 %13, %19, off offset:512 sc0 sc1\n\t"
    "global_load_dwordx4 %14, %19, off offset:2048 sc0 sc1\n\t"
    "global_load_dwordx4 %15, %19, off offset:2560 sc0 sc1\n\t"
    "s_waitcnt vmcnt(0)"
    : "=&v"(q0),"=&v"(q1),"=&v"(q2),"=&v"(q3),"=&v"(q4),"=&v"(q5),"=&v"(q6),"=&v"(q7),
      "=&v"(q8),"=&v"(q9),"=&v"(q10),"=&v"(q11),"=&v"(q12),"=&v"(q13),"=&v"(q14),"=&v"(q15)
    : "v"(b0), "v"(b1), "v"(b2), "v"(b3)
    : "memory");
  const unsigned S = 0xFFFFFFFFu;
  bool bad = false;
#define CK(q) bad |= (q[0]==S)|(q[1]==S)|(q[2]==S)|(q[3]==S)
  CK(q0);CK(q1);CK(q2);CK(q3);CK(q4);CK(q5);CK(q6);CK(q7);
  CK(q8);CK(q9);CK(q10);CK(q11);CK(q12);CK(q13);CK(q14);CK(q15);
#undef CK
  union U { u32x4 u; bf16x8 b; } cv;
  cv.u=q0;  afr0[0]=cv.b; cv.u=q1;  afr1[0]=cv.b; cv.u=q2;  afr0[1]=cv.b; cv.u=q3;  afr1[1]=cv.b;
  cv.u=q4;  afr0[2]=cv.b; cv.u=q5;  afr1[2]=cv.b; cv.u=q6;  afr0[3]=cv.b; cv.u=q7;  afr1[3]=cv.b;
  cv.u=q8;  afr0[4]=cv.b; cv.u=q9;  afr1[4]=cv.b; cv.u=q10; afr0[5]=cv.b; cv.u=q11; afr1[5]=cv.b;
  cv.u=q12; afr0[6]=cv.b; cv.u=q13; afr1[6]=cv.b; cv.u=q14; afr0[7]=cv.b; cv.u=q15; afr1[7]=cv.b;
  return !bad;
}

// ---------------- embedding gather + mask ----------------
__global__ void k_embed(const int* __restrict__ x, const float* __restrict__ tab,
                        unsigned short* __restrict__ emb, int* __restrict__ mask) {
  int t = blockIdx.x, b = blockIdx.y;
  int tok = x[b * S_LEN + t];
  if (threadIdx.x == 0) mask[t * NB + b] = (tok != 0);
  const float4* src = (const float4*)(tab + (size_t)tok * UDIM);
  ushort4* dst = (ushort4*)(emb + ((size_t)t * NB + b) * UDIM);
  int i = threadIdx.x;
  float4 v = src[i];
  ushort4 o;
  o.x = f2bf(v.x); o.y = f2bf(v.y); o.z = f2bf(v.z); o.w = f2bf(v.w);
  dst[i] = o;
}

// ---------------- weight transpose/convert ----------------
__global__ void k_wprep(WPtrs wp, unsigned short* __restrict__ wsW) {
  int bid = blockIdx.x;
  int kt = bid & 31; bid >>= 5;
  int g  = bid % 3;  bid /= 3;
  int wg = bid & 31; bid >>= 5;
  int slab = bid;                        // 0..7 : (chain, mat)
  const float* src = wp.p[slab];
  int tid = threadIdx.x;
  int r = tid >> 4, cc = tid & 15;
  __shared__ float ldsT[16][17];
  ldsT[cc][r] = src[(size_t)(kt * 16 + r) * 1536 + g * 512 + wg * 16 + cc];
  __syncthreads();
  size_t off = ((size_t)slab * WGS + wg) * (48 * 512) + (size_t)(g * 16 + r) * 512 + kt * 16 + cc;
  wsW[off] = f2bf(ldsT[r][cc]);
}

// ---------------- persistent recurrent kernel ----------------
// chains: 0=fw_l0 1=fw_l1 2=bw_l0 3=bw_l1. 32 WGs/chain, each owns 16 h-cols.
// waves: 0:(x@k,Klo) 1:(h@rk,Klo) 2:(x@k,Khi) 3:(h@rk,Khi)
// R14 = R12 hint-first protocol + bank-conflict-free sAcc:
//   - sAcc stride 48->50 (write quads land 8 banks apart -> free 2-way)
//   - combine ownership (j = tid&15, rows b0 and b0+16) -> reads hit
//     consecutive banks (free 2-way); biases in registers (LDS reads gone)
//   - u32 publish preserved via lane-pair __shfl_xor half-exchange
__global__ __launch_bounds__(256, 1) void k_rnn(
    const unsigned short* __restrict__ wsW, const unsigned short* __restrict__ emb,
    unsigned short* __restrict__ hist, const int* __restrict__ mask,
    const float* __restrict__ state, BPtrs bp, float* __restrict__ out) {
  __shared__ short sW[2 * 48 * 512];        // 98304 B, XOR-swizzled rows
  __shared__ float sAcc[2][2][2][32][50];   // [parity][khalf][mat], padded 50
  __shared__ unsigned char sMask[S_LEN][NB];

  int tid = threadIdx.x;
  int bid = blockIdx.x;
  int xcd = bid & 7;                      // perf heuristic only
  int c = xcd >> 1;                       // chain
  int w = ((bid >> 3) << 1) | (xcd & 1);  // wg-in-chain 0..31
  int layer = c & 1;
  bool back = (c >= 2);
  int lane = tid & 63;
  int wave = tid >> 6;
  int mat = wave & 1;                     // 0: x@k, 1: h@rk
  int kh = wave >> 1;                     // K-half

  // combine ownership: thread -> column j, rows b0 and b0+16
  int cj = tid & 15;
  int cb0 = tid >> 4;                     // 0..15
  int col = w * 16 + cj;
  float hreg0, hreg1, preg0 = 0.f, preg1 = 0.f;

  // per-thread biases (fixed column): x-side and h-side z/r/h
  const float* bptr = bp.p[c];
  float bxz = bptr[col], bxr = bptr[512 + col], bxh = bptr[1024 + col];
  float bhz = bptr[1536 + col], bhr = bptr[2048 + col], bhh = bptr[2560 + col];

  char* histc = (char*)hist;

  // ---- init: weights -> LDS (swizzled), mask, state ----
  {
    const size_t slabSz = 48 * 512;
    for (int ch = tid; ch < 2 * 48 * 64; ch += 256) {
      int m = ch / (48 * 64);
      int rem = ch % (48 * 64);
      int nl = rem >> 6;
      int k16 = rem & 63;
      const unsigned short* sp =
          wsW + ((size_t)((c * 2 + m) * WGS) + w) * slabSz + (size_t)nl * 512 + k16 * 8;
      bf16x8 val = *(const bf16x8*)sp;
      int byte = m * 49152 + nl * 1024 + ((k16 * 16) ^ ((nl & 7) << 4));
      *(bf16x8*)((char*)sW + byte) = val;
    }
    for (int i = tid; i < S_LEN * NB; i += 256)
      sMask[i >> 5][i & 31] = (unsigned char)(mask[i] != 0);
    // state -> h registers + publish hist slot 0 (paired u32 pack)
    hreg0 = state[((size_t)c * NB + cb0) * UDIM + col];
    hreg1 = state[((size_t)c * NB + cb0 + 16) * UDIM + col];
    float sendv = (cj & 1) ? hreg0 : hreg1;
    float recv = __shfl_xor(sendv, 1, 64);
    unsigned pk; size_t poff;
    if ((cj & 1) == 0) {  // even lane: row b0, cols (cj, cj+1)
      pk = (unsigned)f2bf(hreg0) | ((unsigned)f2bf(recv) << 16);
      poff = ((size_t)w << 10) + cb0 * 32 + cj * 2;
    } else {              // odd lane: row b0+16, cols (cj-1, cj)
      pk = (unsigned)f2bf(recv) | ((unsigned)f2bf(hreg1) << 16);
      poff = ((size_t)w << 10) + (cb0 + 16) * 32 + (cj - 1) * 2;
    }
    st_u32c(histc + SLAB(c, 0) + poff, pk);
  }
  __syncthreads();   // implicit drain commits slot-0 publish (once, off-loop)

  int r15 = lane & 15, quad = lane >> 4;
  // unit-slab lane base for the 16-batch
  int lbase = ((kh * 16 + (quad >> 1)) << 10) + ((quad & 1) << 4) + r15 * 32;
  // hint sample: lane -> slab (kh*16 + (lane&15)), line (lane>>4)*2+1, last u32
  int hoff = ((kh * 16 + (lane & 15)) << 10) + ((((lane >> 4) << 1) + 1) << 7) + 124;
  bool ownHint = (kh * 16 + (lane & 15)) == w;
  // emb lane base (row-major layout)
  int abase = r15 * UDIM + kh * 256 + quad * 8;
  int matbase = mat * 49152;

  for (int t = 0; t < S_LEN; ++t) {
    int par = t & 1;
    int treal = back ? (S_LEN - 1 - t) : t;

    bf16x8 afr0[8], afr1[8];
    if (mat == 0 && layer == 0) {
      const short* a16 = (const short*)(emb + (size_t)treal * NB * UDIM);
#pragma unroll
      for (int kc = 0; kc < 8; ++kc) {
        afr0[kc] = *(const bf16x8*)(a16 + abase + kc * 32);
        afr1[kc] = *(const bf16x8*)(a16 + abase + 16 * UDIM + kc * 32);
      }
    } else {
      // hint-first (R12): poll one word per needed slab, then batch + validate
      const char* sb;
      bool skipOwn;
      if (mat == 0) { sb = histc + SLAB(c - 1, t + 1); skipOwn = false; }
      else          { sb = histc + SLAB(c, t);          skipOwn = true; }
      const char* hp = sb + hoff;
      bool own = skipOwn && ownHint;
      unsigned hv = own ? 0u : ld_word_coh(hp);
      while (!__all(own || hv != 0xFFFFFFFFu))
        hv = own ? 0u : ld_word_coh(hp);
      const char* b0p = sb + lbase;
      bool ok = ld_slab16(b0p, b0p + 4096, b0p + 8192, b0p + 12288, afr0, afr1);
      while (!__all(ok))
        ok = ld_slab16(b0p, b0p + 4096, b0p + 8192, b0p + 12288, afr0, afr1);
    }

    // GEMM: (32 x 48) += A(32 x 256-half) * W(256-half x 48)
    f32x4 acc[2][3];
#pragma unroll
    for (int a = 0; a < 2; a++)
#pragma unroll
      for (int g = 0; g < 3; g++) acc[a][g] = (f32x4){0.f, 0.f, 0.f, 0.f};
#pragma unroll
    for (int kc = 0; kc < 8; ++kc) {
#pragma unroll
      for (int g = 0; g < 3; ++g) {
        int nl = g * 16 + r15;
        int koff = kh * 512 + kc * 64 + quad * 16;
        int byte = matbase + nl * 1024 + (koff ^ ((nl & 7) << 4));
        bf16x8 bw = *(const bf16x8*)((const char*)sW + byte);
        acc[0][g] = __builtin_amdgcn_mfma_f32_16x16x32_bf16(afr0[kc], bw, acc[0][g], 0, 0, 0);
        acc[1][g] = __builtin_amdgcn_mfma_f32_16x16x32_bf16(afr1[kc], bw, acc[1][g], 0, 0, 0);
      }
    }
#pragma unroll
    for (int mt = 0; mt < 2; ++mt)
#pragma unroll
      for (int g = 0; g < 3; ++g)
#pragma unroll
        for (int rr = 0; rr < 4; ++rr)
          sAcc[par][kh][mat][mt * 16 + quad * 4 + rr][g * 16 + r15] = acc[mt][g][rr];
    __syncthreads();   // the ONLY barrier per step (sAcc parity-buffered)

    // combine + GRU: thread owns column cj, rows cb0 and cb0+16
    float hn0, hn1;
    bool mk0 = sMask[treal][cb0] != 0;
    bool mk1 = sMask[treal][cb0 + 16] != 0;
#pragma unroll
    for (int u = 0; u < 2; ++u) {
      int b = cb0 + u * 16;
      float az = sAcc[par][0][0][b][cj]      + sAcc[par][1][0][b][cj]      + bxz;
      float ar = sAcc[par][0][0][b][16 + cj] + sAcc[par][1][0][b][16 + cj] + bxr;
      float ah = sAcc[par][0][0][b][32 + cj] + sAcc[par][1][0][b][32 + cj] + bxh;
      float iz = sAcc[par][0][1][b][cj]      + sAcc[par][1][1][b][cj]      + bhz;
      float ir = sAcc[par][0][1][b][16 + cj] + sAcc[par][1][1][b][16 + cj] + bhr;
      float ih = sAcc[par][0][1][b][32 + cj] + sAcc[par][1][1][b][32 + cj] + bhh;
      float z = 1.f / (1.f + __expf(-(az + iz)));
      float r = 1.f / (1.f + __expf(-(ar + ir)));
      float pre = ah + r * ih;
      pre = fminf(fmaxf(pre, -30.f), 30.f);
      float e2 = __expf(2.f * pre);
      float hh = (e2 - 1.f) / (e2 + 1.f);
      float hold = (u == 0) ? hreg0 : hreg1;
      bool m = (u == 0) ? mk0 : mk1;
      float hv = z * hold + (1.f - z) * hh;
      hv = m ? hv : hold;
      if (u == 0) hn0 = hv; else hn1 = hv;
    }
    hreg0 = hn0; hreg1 = hn1;

    // publish h(t+1): lane-pair half-exchange -> u32 packed 4B stores
    {
      float sendv = (cj & 1) ? hn0 : hn1;
      float recv = __shfl_xor(sendv, 1, 64);
      unsigned pk; size_t poff;
      if ((cj & 1) == 0) {
        pk = (unsigned)f2bf(hn0) | ((unsigned)f2bf(recv) << 16);
        poff = ((size_t)w << 10) + cb0 * 32 + cj * 2;
      } else {
        pk = (unsigned)f2bf(recv) | ((unsigned)f2bf(hn1) << 16);
        poff = ((size_t)w << 10) + (cb0 + 16) * 32 + (cj - 1) * 2;
      }
      st_u32c(histc + SLAB(c, t + 1) + poff, pk);
    }

    // out-writes (off the publish path)
    if (layer == 1) {
      float o0 = mk0 ? hn0 : preg0;
      float o1 = mk1 ? hn1 : preg1;
      preg0 = o0; preg1 = o1;
      out[((size_t)cb0 * S_LEN + treal) * 1024 + (back ? 512 : 0) + col] = o0;
      out[((size_t)(cb0 + 16) * S_LEN + treal) * 1024 + (back ? 512 : 0) + col] = o1;
    }
    if (t == S_LEN - 1) {
      out[(size_t)NB * S_LEN * 1024 + ((size_t)c * NB + cb0) * UDIM + col] = hn0;
      out[(size_t)NB * S_LEN * 1024 + ((size_t)c * NB + cb0 + 16) * UDIM + col] = hn1;
    }
  }
}

extern "C" void kernel_launch(void* const* d_in, const int* in_sizes, int n_in,
                              void* d_out, int out_size, void* d_ws, size_t ws_size,
                              hipStream_t stream) {
  const int* x = (const int*)d_in[0];
  const float* state = (const float*)d_in[1];
  const float* tab = (const float*)d_in[2];
  WPtrs wp;
  wp.p[0] = (const float*)d_in[3];   // fk0
  wp.p[1] = (const float*)d_in[4];   // frk0
  wp.p[2] = (const float*)d_in[6];   // fk1
  wp.p[3] = (const float*)d_in[7];   // frk1
  wp.p[4] = (const float*)d_in[9];   // bk0
  wp.p[5] = (const float*)d_in[10];  // brk0
  wp.p[6] = (const float*)d_in[12];  // bk1
  wp.p[7] = (const float*)d_in[13];  // brk1
  BPtrs bp;
  bp.p[0] = (const float*)d_in[5];   // fb0
  bp.p[1] = (const float*)d_in[8];   // fb1
  bp.p[2] = (const float*)d_in[11];  // bb0
  bp.p[3] = (const float*)d_in[14];  // bb1
  float* out = (float*)d_out;

  char* ws = (char*)d_ws;
  size_t off = 0;
  unsigned short* wsW = (unsigned short*)(ws + off); off += (size_t)8 * 32 * 48 * 512 * 2;   // 25.2 MB
  unsigned short* embp = (unsigned short*)(ws + off); off += (size_t)S_LEN * NB * UDIM * 2;  // 8.4 MB
  unsigned short* hist = (unsigned short*)(ws + off);
  size_t histBytes = (size_t)4 * 257 * 32 * 1024;      off += histBytes;                     // 33.7 MB
  int* maskp = (int*)(ws + off); off += (size_t)S_LEN * NB * 4;

  hipMemsetAsync(hist, 0xFF, histBytes, stream);   // sentinel-poison write-once h
  k_embed<<<dim3(S_LEN, NB), 128, 0, stream>>>(x, tab, embp, maskp);
  k_wprep<<<8 * 32 * 3 * 32, 256, 0, stream>>>(wp, wsW);
  k_rnn<<<128, 256, 0, stream>>>(wsW, embp, hist, maskp, state, bp, out);
}

// Round 15
// 985.976 us; speedup vs baseline: 1.0334x; 1.0334x over previous
//
#include <hip/hip_runtime.h>
#include <hip/hip_bf16.h>

#define S_LEN 256
#define NB 32
#define UDIM 512
#define WGS 32    // workgroups per chain

typedef __attribute__((ext_vector_type(8))) short bf16x8;
typedef __attribute__((ext_vector_type(4))) float f32x4;
typedef __attribute__((ext_vector_type(4))) unsigned u32x4;

struct WPtrs { const float* p[8]; };
struct BPtrs { const float* p[4]; };

// hist layout: [c][slot][unit][b][j]  -- each unit owns a CONTIGUOUS 1KB slab
#define SLAB(c, slot) ((((size_t)(c) * 257 + (slot)) * 32) << 10)

__device__ __forceinline__ unsigned short f2bf(float f) {
  union { float f; unsigned u; } v; v.f = f;
  unsigned r = v.u + 0x7fffu + ((v.u >> 16) & 1u);
  return (unsigned short)(r >> 16);
}

// ---- coherent (cross-XCD) memory ops ----
__device__ __forceinline__ void st_u32c(void* p, unsigned v) {
  asm volatile("global_store_dword %0, %1, off sc0 sc1" :: "v"(p), "v"(v) : "memory");
}

#define SENT_CHECK \
  const unsigned S = 0xFFFFFFFFu; \
  bool bad = false; \
  bad |= (q0[0]==S)|(q0[1]==S)|(q0[2]==S)|(q0[3]==S); \
  bad |= (q1[0]==S)|(q1[1]==S)|(q1[2]==S)|(q1[3]==S); \
  bad |= (q2[0]==S)|(q2[1]==S)|(q2[2]==S)|(q2[3]==S); \
  bad |= (q3[0]==S)|(q3[1]==S)|(q3[2]==S)|(q3[3]==S); \
  bad |= (q4[0]==S)|(q4[1]==S)|(q4[2]==S)|(q4[3]==S); \
  bad |= (q5[0]==S)|(q5[1]==S)|(q5[2]==S)|(q5[3]==S); \
  bad |= (q6[0]==S)|(q6[1]==S)|(q6[2]==S)|(q6[3]==S); \
  bad |= (q7[0]==S)|(q7[1]==S)|(q7[2]==S)|(q7[3]==S); \
  bad |= (q8[0]==S)|(q8[1]==S)|(q8[2]==S)|(q8[3]==S); \
  bad |= (q9[0]==S)|(q9[1]==S)|(q9[2]==S)|(q9[3]==S); \
  bad |= (q10[0]==S)|(q10[1]==S)|(q10[2]==S)|(q10[3]==S); \
  bad |= (q11[0]==S)|(q11[1]==S)|(q11[2]==S)|(q11[3]==S); \
  bad |= (q12[0]==S)|(q12[1]==S)|(q12[2]==S)|(q12[3]==S); \
  bad |= (q13[0]==S)|(q13[1]==S)|(q13[2]==S)|(q13[3]==S); \
  bad |= (q14[0]==S)|(q14[1]==S)|(q14[2]==S)|(q14[3]==S); \
  bad |= (q15[0]==S)|(q15[1]==S)|(q15[2]==S)|(q15[3]==S);

#define CONVERT_OUT \
  union U { u32x4 u; bf16x8 b; } cv; \
  cv.u=q0;  afr0[0]=cv.b; cv.u=q1;  afr1[0]=cv.b; cv.u=q2;  afr0[1]=cv.b; cv.u=q3;  afr1[1]=cv.b; \
  cv.u=q4;  afr0[2]=cv.b; cv.u=q5;  afr1[2]=cv.b; cv.u=q6;  afr0[3]=cv.b; cv.u=q7;  afr1[3]=cv.b; \
  cv.u=q8;  afr0[4]=cv.b; cv.u=q9;  afr1[4]=cv.b; cv.u=q10; afr0[5]=cv.b; cv.u=q11; afr1[5]=cv.b; \
  cv.u=q12; afr0[6]=cv.b; cv.u=q13; afr1[6]=cv.b; cv.u=q14; afr0[7]=cv.b; cv.u=q15; afr1[7]=cv.b;

// Fused wait+read: one asm loop. Each iteration issues the hint load FIRST,
// then the 16 batch loads; vmcnt(16) waits only for the hint (oldest). On
// hint-miss: drain, re-issue. On hint-hit: vmcnt(0) -- the batch, issued
// concurrently with the successful hint, is already ~complete. Per-word
// sentinel validation still guards commit (write-once, 0xFF-poisoned slots).
__device__ __forceinline__ bool wait_ld16(const char* hp,
                                          const char* b0, const char* b1,
                                          const char* b2, const char* b3,
                                          bf16x8* afr0, bf16x8* afr1) {
  u32x4 q0,q1,q2,q3,q4,q5,q6,q7,q8,q9,q10,q11,q12,q13,q14,q15;
  unsigned hint;
  asm volatile(
    "Lpoll%=:\n\t"
    "global_load_dword %16, %21, off sc0 sc1\n\t"
    "global_load_dwordx4 %0, %17, off sc0 sc1\n\t"
    "global_load_dwordx4 %1, %17, off offset:512 sc0 sc1\n\t"
    "global_load_dwordx4 %2, %17, off offset:2048 sc0 sc1\n\t"
    "global_load_dwordx4 %3, %17, off offset:2560 sc0 sc1\n\t"
    "global_load_dwordx4 %4, %18, off sc0 sc1\n\t"
    "global_load_dwordx4 %5, %18, off offset:512 sc0 sc1\n\t"
    "global_load_dwordx4 %6, %18, off offset:2048 sc0 sc1\n\t"
    "global_load_dwordx4 %7, %18, off offset:2560 sc0 sc1\n\t"
    "global_load_dwordx4 %8, %19, off sc0 sc1\n\t"
    "global_load_dwordx4 %9, %19, off offset:512 sc0 sc1\n\t"
    "global_load_dwordx4 %10, %19, off offset:2048 sc0 sc1\n\t"
    "global_load_dwordx4 %11, %19, off offset:2560 sc0 sc1\n\t"
    "global_load_dwordx4 %12, %20, off sc0 sc1\n\t"
    "global_load_dwordx4 %13, %20, off offset:512 sc0 sc1\n\t"
    "global_load_dwordx4 %14, %20, off offset:2048 sc0 sc1\n\t"
    "global_load_dwordx4 %15, %20, off offset:2560 sc0 sc1\n\t"
    "s_waitcnt vmcnt(16)\n\t"
    "v_cmp_eq_u32 vcc, -1, %16\n\t"
    "s_cbranch_vccz Ldone%=\n\t"
    "s_waitcnt vmcnt(0)\n\t"
    "s_branch Lpoll%=\n\t"
    "Ldone%=:\n\t"
    "s_waitcnt vmcnt(0)"
    : "=&v"(q0),"=&v"(q1),"=&v"(q2),"=&v"(q3),"=&v"(q4),"=&v"(q5),"=&v"(q6),"=&v"(q7),
      "=&v"(q8),"=&v"(q9),"=&v"(q10),"=&v"(q11),"=&v"(q12),"=&v"(q13),"=&v"(q14),"=&v"(q15),
      "=&v"(hint)
    : "v"(b0), "v"(b1), "v"(b2), "v"(b3), "v"(hp)
    : "vcc", "memory");
  SENT_CHECK
  CONVERT_OUT
  return !bad;
}

// Blocking coherent 16-load (fallback/retry); vmcnt(0) INSIDE the asm.
__device__ __forceinline__ bool ld_slab16(const char* b0, const char* b1,
                                          const char* b2, const char* b3,
                                          bf16x8* afr0, bf16x8* afr1) {
  u32x4 q0,q1,q2,q3,q4,q5,q6,q7,q8,q9,q10,q11,q12,q13,q14,q15;
  asm volatile(
    "global_load_dwordx4 %0, %16, off sc0 sc1\n\t"
    "global_load_dwordx4 %1, %16, off offset:512 sc0 sc1\n\t"
    "global_load_dwordx4 %2, %16, off offset:2048 sc0 sc1\n\t"
    "global_load_dwordx4 %3, %16, off offset:2560 sc0 sc1\n\t"
    "global_load_dwordx4 %4, %17, off sc0 sc1\n\t"
    "global_load_dwordx4 %5, %17, off offset:512 sc0 sc1\n\t"
    "global_load_dwordx4 %6, %17, off offset:2048 sc0 sc1\n\t"
    "global_load_dwordx4 %7, %17, off offset:2560 sc0 sc1\n\t"
    "global_load_dwordx4 %8, %18, off sc0 sc1\n\t"
    "global_load_dwordx4 %9, %18, off offset:512 sc0 sc1\n\t"
    "global_load_dwordx4 %10, %18, off offset:2048 sc0 sc1\n\t"
    "global_load_dwordx4 %11, %18, off offset:2560 sc0 sc1\n\t"
    "global_load_dwordx4 %12, %19, off sc0 sc1\n\t"
    "global_load_dwordx4 %13, %19, off offset:512 sc0 sc1\n\t"
    "global_load_dwordx4 %14, %19, off offset:2048 sc0 sc1\n\t"
    "global_load_dwordx4 %15, %19, off offset:2560 sc0 sc1\n\t"
    "s_waitcnt vmcnt(0)"
    : "=&v"(q0),"=&v"(q1),"=&v"(q2),"=&v"(q3),"=&v"(q4),"=&v"(q5),"=&v"(q6),"=&v"(q7),
      "=&v"(q8),"=&v"(q9),"=&v"(q10),"=&v"(q11),"=&v"(q12),"=&v"(q13),"=&v"(q14),"=&v"(q15)
    : "v"(b0), "v"(b1), "v"(b2), "v"(b3)
    : "memory");
  SENT_CHECK
  CONVERT_OUT
  return !bad;
}

// ---------------- embedding gather + mask ----------------
__global__ void k_embed(const int* __restrict__ x, const float* __restrict__ tab,
                        unsigned short* __restrict__ emb, int* __restrict__ mask) {
  int t = blockIdx.x, b = blockIdx.y;
  int tok = x[b * S_LEN + t];
  if (threadIdx.x == 0) mask[t * NB + b] = (tok != 0);
  const float4* src = (const float4*)(tab + (size_t)tok * UDIM);
  ushort4* dst = (ushort4*)(emb + ((size_t)t * NB + b) * UDIM);
  int i = threadIdx.x;
  float4 v = src[i];
  ushort4 o;
  o.x = f2bf(v.x); o.y = f2bf(v.y); o.z = f2bf(v.z); o.w = f2bf(v.w);
  dst[i] = o;
}

// ---------------- weight transpose/convert ----------------
__global__ void k_wprep(WPtrs wp, unsigned short* __restrict__ wsW) {
  int bid = blockIdx.x;
  int kt = bid & 31; bid >>= 5;
  int g  = bid % 3;  bid /= 3;
  int wg = bid & 31; bid >>= 5;
  int slab = bid;                        // 0..7 : (chain, mat)
  const float* src = wp.p[slab];
  int tid = threadIdx.x;
  int r = tid >> 4, cc = tid & 15;
  __shared__ float ldsT[16][17];
  ldsT[cc][r] = src[(size_t)(kt * 16 + r) * 1536 + g * 512 + wg * 16 + cc];
  __syncthreads();
  size_t off = ((size_t)slab * WGS + wg) * (48 * 512) + (size_t)(g * 16 + r) * 512 + kt * 16 + cc;
  wsW[off] = f2bf(ldsT[r][cc]);
}

// ---------------- persistent recurrent kernel ----------------
// chains: 0=fw_l0 1=fw_l1 2=bw_l0 3=bw_l1. 32 WGs/chain, each owns 16 h-cols.
// waves: 0:(x@k,Klo) 1:(h@rk,Klo) 2:(x@k,Khi) 3:(h@rk,Khi)
// R15 = R12 (hint-first, no flags, unit-slab hist) with the hint poll and the
// batch read FUSED in one asm loop: batch loads fly concurrently with every
// hint poll, so on detection the data is already ~here (saves the serial RT).
__global__ __launch_bounds__(256, 1) void k_rnn(
    const unsigned short* __restrict__ wsW, const unsigned short* __restrict__ emb,
    unsigned short* __restrict__ hist, const int* __restrict__ mask,
    const float* __restrict__ state, BPtrs bp, float* __restrict__ out) {
  __shared__ short sW[2 * 48 * 512];        // 98304 B, XOR-swizzled rows
  __shared__ float sAcc[2][2][2][32][48];   // [parity][khalf][mat]
  __shared__ float sBias[2][48];
  __shared__ unsigned char sMask[S_LEN][NB];

  int tid = threadIdx.x;
  int bid = blockIdx.x;
  int xcd = bid & 7;                      // perf heuristic only
  int c = xcd >> 1;                       // chain
  int w = ((bid >> 3) << 1) | (xcd & 1);  // wg-in-chain 0..31
  int layer = c & 1;
  bool back = (c >= 2);
  int lane = tid & 63;
  int wave = tid >> 6;
  int mat = wave & 1;                     // 0: x@k, 1: h@rk
  int kh = wave >> 1;                     // K-half

  // combine-phase ownership: thread -> (b, j0, j0+1); h and prev in registers
  int cb = tid >> 3;
  int cj = (tid & 7) << 1;
  float hreg0, hreg1, preg0 = 0.f, preg1 = 0.f;

  char* histc = (char*)hist;

  // ---- init: weights -> LDS (swizzled), biases, mask, state ----
  {
    const size_t slabSz = 48 * 512;
    for (int ch = tid; ch < 2 * 48 * 64; ch += 256) {
      int m = ch / (48 * 64);
      int rem = ch % (48 * 64);
      int nl = rem >> 6;
      int k16 = rem & 63;
      const unsigned short* sp =
          wsW + ((size_t)((c * 2 + m) * WGS) + w) * slabSz + (size_t)nl * 512 + k16 * 8;
      bf16x8 val = *(const bf16x8*)sp;
      int byte = m * 49152 + nl * 1024 + ((k16 * 16) ^ ((nl & 7) << 4));
      *(bf16x8*)((char*)sW + byte) = val;
    }
    const float* bptr = bp.p[c];
    for (int i = tid; i < 96; i += 256) {
      int m = i / 48, nl = i % 48;
      int col = (nl / 16) * 512 + w * 16 + (nl & 15);
      sBias[m][nl] = bptr[m * 1536 + col];
    }
    for (int i = tid; i < S_LEN * NB; i += 256)
      sMask[i >> 5][i & 31] = (unsigned char)(mask[i] != 0);
    // state -> h registers + publish hist slot 0 (contiguous unit slab)
    int col = w * 16 + cj;
    hreg0 = state[((size_t)c * NB + cb) * UDIM + col];
    hreg1 = state[((size_t)c * NB + cb) * UDIM + col + 1];
    unsigned pk = (unsigned)f2bf(hreg0) | ((unsigned)f2bf(hreg1) << 16);
    st_u32c(histc + SLAB(c, 0) + ((size_t)w << 10) + cb * 32 + cj * 2, pk);
  }
  __syncthreads();   // implicit drain commits slot-0 publish (once, off-loop)

  int r15 = lane & 15, quad = lane >> 4;
  // unit-slab lane base for the 16-batch
  int lbase = ((kh * 16 + (quad >> 1)) << 10) + ((quad & 1) << 4) + r15 * 32;
  // hint sample: lane -> slab (kh*16 + (lane&15)), line (lane>>4)*2+1, last u32
  int hoff = ((kh * 16 + (lane & 15)) << 10) + ((((lane >> 4) << 1) + 1) << 7) + 124;
  // emb lane base (row-major layout)
  int abase = r15 * UDIM + kh * 256 + quad * 8;
  int matbase = mat * 49152;

  for (int t = 0; t < S_LEN; ++t) {
    int par = t & 1;
    int treal = back ? (S_LEN - 1 - t) : t;

    bf16x8 afr0[8], afr1[8];
    if (mat == 0 && layer == 0) {
      // layer0 x: plain cached reads of emb
      const short* a16 = (const short*)(emb + (size_t)treal * NB * UDIM);
#pragma unroll
      for (int kc = 0; kc < 8; ++kc) {
        afr0[kc] = *(const bf16x8*)(a16 + abase + kc * 32);
        afr1[kc] = *(const bf16x8*)(a16 + abase + 16 * UDIM + kc * 32);
      }
    } else {
      // h (mat1) or layer1-x: fused hint+batch poll loop, then rare retry
      const char* sb;
      if (mat == 0) sb = histc + SLAB(c - 1, t + 1);
      else          sb = histc + SLAB(c, t);
      const char* hp = sb + hoff;
      const char* b0p = sb + lbase;
      bool ok = wait_ld16(hp, b0p, b0p + 4096, b0p + 8192, b0p + 12288, afr0, afr1);
      while (!__all(ok))
        ok = ld_slab16(b0p, b0p + 4096, b0p + 8192, b0p + 12288, afr0, afr1);
    }

    // GEMM: (32 x 48) += A(32 x 256-half) * W(256-half x 48)
    f32x4 acc[2][3];
#pragma unroll
    for (int a = 0; a < 2; a++)
#pragma unroll
      for (int g = 0; g < 3; g++) acc[a][g] = (f32x4){0.f, 0.f, 0.f, 0.f};
#pragma unroll
    for (int kc = 0; kc < 8; ++kc) {
#pragma unroll
      for (int g = 0; g < 3; ++g) {
        int nl = g * 16 + r15;
        int koff = kh * 512 + kc * 64 + quad * 16;
        int byte = matbase + nl * 1024 + (koff ^ ((nl & 7) << 4));
        bf16x8 bw = *(const bf16x8*)((const char*)sW + byte);
        acc[0][g] = __builtin_amdgcn_mfma_f32_16x16x32_bf16(afr0[kc], bw, acc[0][g], 0, 0, 0);
        acc[1][g] = __builtin_amdgcn_mfma_f32_16x16x32_bf16(afr1[kc], bw, acc[1][g], 0, 0, 0);
      }
    }
#pragma unroll
    for (int mt = 0; mt < 2; ++mt)
#pragma unroll
      for (int g = 0; g < 3; ++g)
#pragma unroll
        for (int rr = 0; rr < 4; ++rr)
          sAcc[par][kh][mat][mt * 16 + quad * 4 + rr][g * 16 + r15] = acc[mt][g][rr];
    __syncthreads();   // the ONLY barrier per step (sAcc parity-buffered)

    // combine + GRU nonlinearity: this thread owns (cb, cj) and (cb, cj+1)
    float hn0, hn1;
    bool mk;
    {
      int b = cb, j0 = cj;
      mk = sMask[treal][b] != 0;
#pragma unroll
      for (int u = 0; u < 2; ++u) {
        int j = j0 + u;
        float az = sAcc[par][0][0][b][j]      + sAcc[par][1][0][b][j]      + sBias[0][j];
        float ar = sAcc[par][0][0][b][16 + j] + sAcc[par][1][0][b][16 + j] + sBias[0][16 + j];
        float ah = sAcc[par][0][0][b][32 + j] + sAcc[par][1][0][b][32 + j] + sBias[0][32 + j];
        float iz = sAcc[par][0][1][b][j]      + sAcc[par][1][1][b][j]      + sBias[1][j];
        float ir = sAcc[par][0][1][b][16 + j] + sAcc[par][1][1][b][16 + j] + sBias[1][16 + j];
        float ih = sAcc[par][0][1][b][32 + j] + sAcc[par][1][1][b][32 + j] + sBias[1][32 + j];
        float z = 1.f / (1.f + __expf(-(az + iz)));
        float r = 1.f / (1.f + __expf(-(ar + ir)));
        float pre = ah + r * ih;
        pre = fminf(fmaxf(pre, -30.f), 30.f);
        float e2 = __expf(2.f * pre);
        float hh = (e2 - 1.f) / (e2 + 1.f);
        float hold = (u == 0) ? hreg0 : hreg1;
        float hv = z * hold + (1.f - z) * hh;
        hv = mk ? hv : hold;
        if (u == 0) hn0 = hv; else hn1 = hv;
      }
      hreg0 = hn0; hreg1 = hn1;
      // publish h(t+1) into OUR contiguous slab: fire-and-forget, no drain
      unsigned pk = (unsigned)f2bf(hn0) | ((unsigned)f2bf(hn1) << 16);
      st_u32c(histc + SLAB(c, t + 1) + ((size_t)w << 10) + cb * 32 + cj * 2, pk);
    }

    // out-writes (off the publish path)
    if (layer == 1) {
      float o0 = mk ? hn0 : preg0;
      float o1 = mk ? hn1 : preg1;
      preg0 = o0; preg1 = o1;
      *(float2*)(out + ((size_t)cb * S_LEN + treal) * 1024 + (back ? 512 : 0) + w * 16 + cj) =
          make_float2(o0, o1);
    }
    if (t == S_LEN - 1) {
      *(float2*)(out + (size_t)NB * S_LEN * 1024 + ((size_t)c * NB + cb) * UDIM + w * 16 + cj) =
          make_float2(hn0, hn1);
    }
  }
}

extern "C" void kernel_launch(void* const* d_in, const int* in_sizes, int n_in,
                              void* d_out, int out_size, void* d_ws, size_t ws_size,
                              hipStream_t stream) {
  const int* x = (const int*)d_in[0];
  const float* state = (const float*)d_in[1];
  const float* tab = (const float*)d_in[2];
  WPtrs wp;
  wp.p[0] = (const float*)d_in[3];   // fk0
  wp.p[1] = (const float*)d_in[4];   // frk0
  wp.p[2] = (const float*)d_in[6];   // fk1
  wp.p[3] = (const float*)d_in[7];   // frk1
  wp.p[4] = (const float*)d_in[9];   // bk0
  wp.p[5] = (const float*)d_in[10];  // brk0
  wp.p[6] = (const float*)d_in[12];  // bk1
  wp.p[7] = (const float*)d_in[13];  // brk1
  BPtrs bp;
  bp.p[0] = (const float*)d_in[5];   // fb0
  bp.p[1] = (const float*)d_in[8];   // fb1
  bp.p[2] = (const float*)d_in[11];  // bb0
  bp.p[3] = (const float*)d_in[14];  // bb1
  float* out = (float*)d_out;

  char* ws = (char*)d_ws;
  size_t off = 0;
  unsigned short* wsW = (unsigned short*)(ws + off); off += (size_t)8 * 32 * 48 * 512 * 2;   // 25.2 MB
  unsigned short* embp = (unsigned short*)(ws + off); off += (size_t)S_LEN * NB * UDIM * 2;  // 8.4 MB
  unsigned short* hist = (unsigned short*)(ws + off);
  size_t histBytes = (size_t)4 * 257 * 32 * 1024;      off += histBytes;                     // 33.7 MB
  int* maskp = (int*)(ws + off); off += (size_t)S_LEN * NB * 4;

  hipMemsetAsync(hist, 0xFF, histBytes, stream);   // sentinel-poison write-once h
  k_embed<<<dim3(S_LEN, NB), 128, 0, stream>>>(x, tab, embp, maskp);
  k_wprep<<<8 * 32 * 3 * 32, 256, 0, stream>>>(wp, wsW);
  k_rnn<<<128, 256, 0, stream>>>(wsW, embp, hist, maskp, state, bp, out);
}